// Round 5
// baseline (170.769 us; speedup 1.0000x reference)
//
#include <hip/hip_runtime.h>

// out[b, I[e]] += inputs[b, J[e]] * W3[e] * velocity[J[e]]; out += bias
// R2: edge atomics = 204.8MB atomic-path traffic (bound). R3: exact CSR killed
// atomics but 9-dispatch build cost more than it saved; gather latency-bound.
// R4: 1-dispatch bucket build + high-occupancy gather -> 161.7us; k_build now
// dominates (49us) with WRITE_SIZE 47MB =~ one 64B line eviction per 8B record
// (bucket array 12.8MB > 4MB XCD L2, cross-XCD line bounce, no merge).
// R5: non-temporal stores/loads on all single-use streams (bucket records,
// edge metadata, bucket reads, final out) -> masked fabric writes merged in
// memory-side Infinity Cache; also keeps in_T resident in L2 during gather.

#define BATCH 64
#define SEG_ROWS 4          // rows per bucket/wave
#define CAP 128             // bucket capacity (Poisson mean 64, max ~97)
#define OVF_CAP 4096        // spill buffer capacity

// ---- K1: transpose inputs [B,N] -> in_T [N,B]; zero bucket counts ----
__global__ void k_prep(const float* __restrict__ in, float* __restrict__ in_T,
                       int* __restrict__ cnt, int nseg, int N) {
    const int gid = blockIdx.x * 256 + threadIdx.x;
    if (gid < nseg) cnt[gid] = 0;
    if (gid == nseg) cnt[nseg] = 0;          // overflow counter lives at cnt[nseg]

    __shared__ float tile[64 * 65];
    const int n0 = blockIdx.x * 64;
    const int t  = threadIdx.x;
    const int x  = t & 63;
    const int r  = t >> 6;
    for (int b = r; b < BATCH; b += 4) {
        float v = 0.f;
        if (n0 + x < N) v = in[(size_t)b * N + n0 + x];
        tile[x * 65 + b] = v;
    }
    __syncthreads();
    for (int xr = r; xr < 64; xr += 4) {
        if (n0 + xr < N) in_T[(size_t)(n0 + xr) * BATCH + x] = tile[xr * 65 + x];
    }
}

// ---- K2: bucket build. record u64: lo32 = (i&3)<<16 | j, hi32 = bits(w) ----
__global__ void k_build(const int* __restrict__ I, const int* __restrict__ J,
                        const float* __restrict__ W3, const float* __restrict__ velocity,
                        int* __restrict__ cnt, unsigned long long* __restrict__ buckets,
                        uint4* __restrict__ ovf, int nseg, int E) {
    const int e = blockIdx.x * blockDim.x + threadIdx.x;
    if (e >= E) return;
    const int iv = __builtin_nontemporal_load(&I[e]);     // single-use streams:
    const int jv = __builtin_nontemporal_load(&J[e]);     // don't pollute L2
    const float w3 = __builtin_nontemporal_load(&W3[e]);
    const float w = w3 * velocity[jv];                    // velocity: hot, cacheable
    const int seg = iv >> 2;
    const int pos = atomicAdd(&cnt[seg], 1);
    if (pos < CAP) {
        const unsigned long long rec =
            ((unsigned long long)__float_as_uint(w) << 32)
            | (((unsigned)(iv & 3) << 16) | (unsigned)jv);
        // nt store: masked fabric write merged in Infinity Cache, no L2
        // line allocate/evict per record.
        __builtin_nontemporal_store(rec, &buckets[(size_t)seg * CAP + pos]);
    } else {
        const int op = atomicAdd(&cnt[nseg], 1);
        if (op < OVF_CAP) ovf[op] = make_uint4((unsigned)iv, (unsigned)jv, __float_as_uint(w), 0u);
    }
}

// ---- K3: gather. Block = 4 waves = 4 segments = 16 output rows.
// Wave streams its bucket with 8-wide batched shfl->load, accumulates into the
// block LDS tile (wave-private rows), epilogue adds bias and stores out[B,N].
__global__ void __launch_bounds__(256) k_gather(
        const float* __restrict__ in_T, const unsigned long long* __restrict__ buckets,
        const int* __restrict__ cnt, const float* __restrict__ bias,
        float* __restrict__ out, int nseg, int N) {
    __shared__ float tile[16 * 65];
    const int t    = threadIdx.x;
    const int lane = t & 63;
    const int w    = t >> 6;                 // wave 0..3
    const int seg  = blockIdx.x * 4 + w;

    for (int idx = t; idx < 16 * 65; idx += 256) tile[idx] = 0.f;
    __syncthreads();

    if (seg < nseg) {
        const int wrow0 = w * 4;             // this wave's first local row
        int c = cnt[seg]; if (c > CAP) c = CAP;
        const unsigned long long* bk = buckets + (size_t)seg * CAP;

        for (int base = 0; base < c; base += 64) {
            int cc = c - base; if (cc > 64) cc = 64;
            unsigned long long rec = 0ull;           // pad -> harmless add to row0 w=0
            if (lane < cc) rec = __builtin_nontemporal_load(&bk[base + lane]);
            const int rlo = (int)(unsigned)(rec & 0xffffffffu);
            const int rhi = (int)(unsigned)(rec >> 32);
            // k0 <= 56 always (cc <= 64), so shfl index k0+u <= 63: in range.
            for (int k0 = 0; k0 < cc; k0 += 8) {
                float v[8], ww[8]; int li[8];
                #pragma unroll
                for (int u = 0; u < 8; ++u) {
                    const int k = k0 + u;
                    const unsigned ij = (unsigned)__shfl(rlo, k);
                    ww[u] = __uint_as_float((unsigned)__shfl(rhi, k));
                    li[u] = (int)(ij >> 16);
                    const int j = (int)(ij & 0xffffu);
                    v[u] = in_T[j * BATCH + lane];   // 8 independent loads in flight
                }
                #pragma unroll
                for (int u = 0; u < 8; ++u) {
                    tile[(wrow0 + li[u]) * 65 + lane] += v[u] * ww[u];
                }
            }
        }
    }
    __syncthreads();

    // epilogue: rows [n0, n0+16) -> out[b*N+n] + bias, 64B segments per b.
    // nt store: out is never re-read; keep in_T resident in L2.
    const int n0 = blockIdx.x * 16;
    const int c16 = t & 15;                  // column within the 16-row strip
    const int bq  = t >> 4;                  // 0..15
    const int n = n0 + c16;
    if (n < N) {
        const float bv = bias[n];
        for (int b = bq; b < BATCH; b += 16)
            __builtin_nontemporal_store(tile[c16 * 65 + b] + bv, &out[(size_t)b * N + n]);
    }
}

// ---- K4: replay spilled edges (normally zero) ----
__global__ void k_overflow(const float* __restrict__ in_T, const uint4* __restrict__ ovf,
                           const int* __restrict__ cnt, int nseg,
                           float* __restrict__ out, int N) {
    const int lane = threadIdx.x & 63;
    const int wv   = (blockIdx.x * blockDim.x + threadIdx.x) >> 6;
    const int nw   = (gridDim.x * blockDim.x) >> 6;
    int novf = cnt[nseg]; if (novf > OVF_CAP) novf = OVF_CAP;
    for (int r = wv; r < novf; r += nw) {
        const uint4 rec = ovf[r];
        const float val = in_T[rec.y * BATCH + lane] * __uint_as_float(rec.z);
        atomicAdd(&out[(size_t)lane * N + rec.x], val);
    }
}

// ---- fallback path (ws too small or N doesn't fit u16): direct atomics ----
__global__ void k_edge_scatter_direct(const float* __restrict__ in,
                                      const float* __restrict__ W3,
                                      const float* __restrict__ velocity,
                                      const int* __restrict__ I,
                                      const int* __restrict__ J,
                                      float* __restrict__ out, int N, int E) {
    const int lane = threadIdx.x & 63;
    const long wave   = (long)blockIdx.x * (blockDim.x >> 6) + (threadIdx.x >> 6);
    const long nwaves = (long)gridDim.x * (blockDim.x >> 6);
    for (long base = wave * 64; base < E; base += nwaves * 64) {
        const long e = base + lane;
        int iv = 0, jv = 0; float wvv = 0.f;
        if (e < E) { iv = I[e]; jv = J[e]; wvv = W3[e] * velocity[jv]; }
        const int cnt = (int)((E - base) < 64 ? (E - base) : 64);
        for (int k = 0; k < cnt; ++k) {
            const int   ii = __shfl(iv, k);
            const int   jj = __shfl(jv, k);
            const float wvx = __shfl(wvv, k);
            const float val = in[(size_t)lane * N + jj] * wvx;
            atomicAdd(&out[(size_t)lane * N + ii], val);
        }
    }
}

__global__ void k_add_bias(const float* __restrict__ bias, float* __restrict__ out, int N, int total) {
    int idx = blockIdx.x * blockDim.x + threadIdx.x;
    if (idx < total) out[idx] += bias[idx % N];
}

extern "C" void kernel_launch(void* const* d_in, const int* in_sizes, int n_in,
                              void* d_out, int out_size, void* d_ws, size_t ws_size,
                              hipStream_t stream) {
    const float* inputs   = (const float*)d_in[0];
    const float* W3       = (const float*)d_in[1];
    const float* bias     = (const float*)d_in[2];
    const float* velocity = (const float*)d_in[3];
    const int*   I        = (const int*)d_in[4];
    const int*   J        = (const int*)d_in[5];
    const int E = in_sizes[1];
    const int N = in_sizes[3];
    float* out = (float*)d_out;

    const size_t mat_elems = (size_t)N * BATCH;
    const int nseg = (N + SEG_ROWS - 1) / SEG_ROWS;
    const int nb_n = (N + 63) / 64;
    const int nb_e = (E + 255) / 256;
    const int nb_g = (nseg + 3) / 4;

    // ws: in_T | buckets | cnt[nseg+1] | ovf
    const size_t need = mat_elems * sizeof(float)
                      + (size_t)nseg * CAP * sizeof(unsigned long long)
                      + ((size_t)nseg + 1) * sizeof(int)
                      + (size_t)OVF_CAP * sizeof(uint4);

    if (ws_size >= need && N <= 65535) {
        float* in_T = (float*)d_ws;
        unsigned long long* buckets = (unsigned long long*)(in_T + mat_elems);
        int*   cnt = (int*)(buckets + (size_t)nseg * CAP);
        uint4* ovf = (uint4*)(cnt + nseg + 1);

        k_prep    <<<nb_n, 256, 0, stream>>>(inputs, in_T, cnt, nseg, N);
        k_build   <<<nb_e, 256, 0, stream>>>(I, J, W3, velocity, cnt, buckets, ovf, nseg, E);
        k_gather  <<<nb_g, 256, 0, stream>>>(in_T, buckets, cnt, bias, out, nseg, N);
        k_overflow<<<16,   256, 0, stream>>>(in_T, ovf, cnt, nseg, out, N);
    } else {
        hipMemsetAsync(out, 0, (size_t)out_size * sizeof(float), stream);
        const int waves_needed   = (E + 63) / 64;
        const int scatter_blocks = (waves_needed + 3) / 4;
        k_edge_scatter_direct<<<scatter_blocks, 256, 0, stream>>>(inputs, W3, velocity, I, J, out, N, E);
        k_add_bias<<<(out_size + 255) / 256, 256, 0, stream>>>(bias, out, N, out_size);
    }
}

// Round 6
// 157.117 us; speedup vs baseline: 1.0869x; 1.0869x over previous
//
#include <hip/hip_runtime.h>

// out[b, I[e]] += inputs[b, J[e]] * W3[e] * velocity[J[e]]; out += bias
// R2: per-edge atomics = 204.8MB atomic-path traffic (bound).
// R4: bucket build + high-occupancy gather -> 161.7us; k_build dominates
//     (49us): WRITE 47MB = one 64B line eviction per scattered 8B record.
// R5: nt stores FALSIFIED (WRITE rose to 53MB, build 54us) - nt = no-allocate
//     => immediate partial-line fabric writes. Reverted everywhere.
// R6: two-pass counting sort with LDS staging so all global writes are DENSE:
//     pass1 partitions edges into 256-row coarse buckets via per-block LDS
//     histogram + one cursor atomicAdd per (block,bucket) => contiguous ~84B
//     runs, block-exclusive lines. pass2 = one block per coarse bucket sorts
//     its ~32KB window by 4-row segment (L2-resident scatter, full-line
//     writebacks) and emits exact seg_start[]. Gather = R4 structure, dense
//     records, no CAP holes, no overflow kernel.

#define BATCH 64
#define SEG_ROWS 4            // rows per segment (= per gather wave)
#define ROWS_PC 256           // rows per coarse bucket (pass-1 bin)
#define SEGS_PC 64            // segments per coarse bucket
#define PCHUNK 2048           // edges per pass-1 block

typedef unsigned long long ull;

// ---- K1: transpose inputs [B,N] -> in_T [N,B]; zero coarse histogram ----
__global__ void k_prep(const float* __restrict__ in, float* __restrict__ in_T,
                       int* __restrict__ coarse_hist, int NC, int N) {
    const int gid = blockIdx.x * 256 + threadIdx.x;
    if (gid < NC) coarse_hist[gid] = 0;

    __shared__ float tile[64 * 65];
    const int n0 = blockIdx.x * 64;
    const int t  = threadIdx.x;
    const int x  = t & 63;
    const int r  = t >> 6;
    for (int b = r; b < BATCH; b += 4) {
        float v = 0.f;
        if (n0 + x < N) v = in[(size_t)b * N + n0 + x];
        tile[x * 65 + b] = v;
    }
    __syncthreads();
    for (int xr = r; xr < 64; xr += 4) {
        if (n0 + xr < N) in_T[(size_t)(n0 + xr) * BATCH + x] = tile[xr * 65 + x];
    }
}

// ---- K2: coarse histogram (LDS-aggregated) ----
__global__ void k_hist(const int* __restrict__ I, int* __restrict__ coarse_hist, int E) {
    __shared__ int h[256];
    const int t = threadIdx.x;
    h[t] = 0;
    __syncthreads();
    const int e0 = blockIdx.x * PCHUNK;
    int e1 = e0 + PCHUNK; if (e1 > E) e1 = E;
    for (int e = e0 + t; e < e1; e += 256) atomicAdd(&h[I[e] >> 8], 1);
    __syncthreads();
    if (h[t]) atomicAdd(&coarse_hist[t], h[t]);
}

// ---- K3: exclusive scan of NC (<=256) coarse counts; init cursors ----
__global__ void k_scan(const int* __restrict__ coarse_hist, int* __restrict__ coarse_base,
                       int* __restrict__ gcursor, int NC) {
    __shared__ int sh[256];
    const int t = threadIdx.x;
    const int v = (t < NC) ? coarse_hist[t] : 0;
    sh[t] = v;
    __syncthreads();
    for (int off = 1; off < 256; off <<= 1) {
        const int u = (t >= off) ? sh[t - off] : 0;
        __syncthreads();
        sh[t] += u;
        __syncthreads();
    }
    if (t < NC) { coarse_base[t] = sh[t] - v; gcursor[t] = sh[t] - v; }
    if (t == NC - 1) coarse_base[NC] = sh[t];   // = E
}

// ---- K4: pass-1 partition into coarse buckets (dense run reservations) ----
// record u64: hi32 = bits(w), lo32 = (i & 255) << 16 | j
__global__ void k_partition(const int* __restrict__ I, const int* __restrict__ J,
                            const float* __restrict__ W3, const float* __restrict__ velocity,
                            int* __restrict__ gcursor, ull* __restrict__ part, int E) {
    __shared__ int hist[256];
    __shared__ int base[256];
    const int t = threadIdx.x;
    hist[t] = 0;
    __syncthreads();
    const int e0 = blockIdx.x * PCHUNK;
    int e1 = e0 + PCHUNK; if (e1 > E) e1 = E;
    for (int e = e0 + t; e < e1; e += 256) atomicAdd(&hist[I[e] >> 8], 1);
    __syncthreads();
    const int cnt = hist[t];
    base[t] = cnt ? atomicAdd(&gcursor[t], cnt) : 0;   // one reservation per (block,bucket)
    __syncthreads();
    hist[t] = 0;                                        // reuse as rank counters
    __syncthreads();
    for (int e = e0 + t; e < e1; e += 256) {
        const int   i = I[e];
        const int   j = J[e];
        const float w = W3[e] * velocity[j];
        const int   c = i >> 8;
        const int   r = atomicAdd(&hist[c], 1);
        const unsigned lo = ((unsigned)(i & 255) << 16) | (unsigned)j;
        part[(size_t)base[c] + r] = ((ull)__float_as_uint(w) << 32) | lo;
    }
}

// ---- K5: pass-2 fine sort within one coarse bucket; emit seg_start ----
// final record u64: hi32 = bits(w), lo32 = (i & 3) << 16 | j
__global__ void k_finesort(const ull* __restrict__ part, const int* __restrict__ coarse_base,
                           ull* __restrict__ edges, int* __restrict__ seg_start) {
    const int c   = blockIdx.x;
    const int beg = coarse_base[c];
    const int end = coarse_base[c + 1];
    __shared__ int h[SEGS_PC];
    __shared__ int cur[SEGS_PC];
    const int t = threadIdx.x;
    if (t < SEGS_PC) h[t] = 0;
    __syncthreads();
    for (int e = beg + t; e < end; e += blockDim.x) {
        const unsigned lo = (unsigned)part[e];
        atomicAdd(&h[(lo >> 18) & 63], 1);         // seg-local id = localrow >> 2
    }
    __syncthreads();
    if (t < SEGS_PC) {                              // wave-0 prefix scan over 64 bins
        const int v = h[t];
        int s = v;
        for (int off = 1; off < SEGS_PC; off <<= 1) {
            const int u = __shfl_up(s, off);
            if (t >= off) s += u;
        }
        const int excl = s - v;
        cur[t] = excl;
        seg_start[c * SEGS_PC + t] = beg + excl;
    }
    __syncthreads();
    for (int e = beg + t; e < end; e += blockDim.x) {
        const ull rec = part[e];
        const unsigned lo = (unsigned)rec;
        const int s = (lo >> 18) & 63;
        const int pos = beg + atomicAdd(&cur[s], 1);
        edges[pos] = (rec & 0xffffffff00000000ull) | (ull)(lo & 0x3ffffu);
    }
}

// ---- K6: gather. Block = 4 waves = 4 segments = 16 output rows. ----
__global__ void __launch_bounds__(256) k_gather(
        const float* __restrict__ in_T, const ull* __restrict__ edges,
        const int* __restrict__ seg_start, const float* __restrict__ bias,
        float* __restrict__ out, int nseg, int N) {
    __shared__ float tile[16 * 65];
    const int t    = threadIdx.x;
    const int lane = t & 63;
    const int w    = t >> 6;                 // wave 0..3
    const int seg  = blockIdx.x * 4 + w;

    for (int idx = t; idx < 16 * 65; idx += 256) tile[idx] = 0.f;
    __syncthreads();

    if (seg < nseg) {
        const int wrow0 = w * 4;             // this wave's first local row
        const int ebeg = seg_start[seg];
        const int eend = seg_start[seg + 1];

        for (int base = ebeg; base < eend; base += 64) {
            int cc = eend - base; if (cc > 64) cc = 64;
            ull rec = 0ull;                          // pad -> harmless add to row0 w=0
            if (lane < cc) rec = edges[base + lane];
            const int rlo = (int)(unsigned)(rec & 0xffffffffu);
            const int rhi = (int)(unsigned)(rec >> 32);
            for (int k0 = 0; k0 < cc; k0 += 8) {
                float v[8], ww[8]; int li[8];
                #pragma unroll
                for (int u = 0; u < 8; ++u) {
                    const int k = k0 + u;
                    const unsigned ij = (unsigned)__shfl(rlo, k);
                    ww[u] = __uint_as_float((unsigned)__shfl(rhi, k));
                    li[u] = (int)(ij >> 16);         // 2 bits: row-in-seg
                    const int j = (int)(ij & 0xffffu);
                    v[u] = in_T[j * BATCH + lane];   // 8 independent loads in flight
                }
                #pragma unroll
                for (int u = 0; u < 8; ++u) {
                    tile[(wrow0 + li[u]) * 65 + lane] += v[u] * ww[u];
                }
            }
        }
    }
    __syncthreads();

    // epilogue: rows [n0, n0+16) -> out[b*N+n] + bias, coalesced per b
    const int n0  = blockIdx.x * 16;
    const int c16 = t & 15;
    const int bq  = t >> 4;
    const int n = n0 + c16;
    if (n < N) {
        const float bv = bias[n];
        for (int b = bq; b < BATCH; b += 16)
            out[(size_t)b * N + n] = tile[c16 * 65 + b] + bv;
    }
}

// ---- fallback path (ws too small or N doesn't fit u16): direct atomics ----
__global__ void k_edge_scatter_direct(const float* __restrict__ in,
                                      const float* __restrict__ W3,
                                      const float* __restrict__ velocity,
                                      const int* __restrict__ I,
                                      const int* __restrict__ J,
                                      float* __restrict__ out, int N, int E) {
    const int lane = threadIdx.x & 63;
    const long wave   = (long)blockIdx.x * (blockDim.x >> 6) + (threadIdx.x >> 6);
    const long nwaves = (long)gridDim.x * (blockDim.x >> 6);
    for (long base = wave * 64; base < E; base += nwaves * 64) {
        const long e = base + lane;
        int iv = 0, jv = 0; float wvv = 0.f;
        if (e < E) { iv = I[e]; jv = J[e]; wvv = W3[e] * velocity[jv]; }
        const int cnt = (int)((E - base) < 64 ? (E - base) : 64);
        for (int k = 0; k < cnt; ++k) {
            const int   ii = __shfl(iv, k);
            const int   jj = __shfl(jv, k);
            const float wvx = __shfl(wvv, k);
            const float val = in[(size_t)lane * N + jj] * wvx;
            atomicAdd(&out[(size_t)lane * N + ii], val);
        }
    }
}

__global__ void k_add_bias(const float* __restrict__ bias, float* __restrict__ out, int N, int total) {
    int idx = blockIdx.x * blockDim.x + threadIdx.x;
    if (idx < total) out[idx] += bias[idx % N];
}

extern "C" void kernel_launch(void* const* d_in, const int* in_sizes, int n_in,
                              void* d_out, int out_size, void* d_ws, size_t ws_size,
                              hipStream_t stream) {
    const float* inputs   = (const float*)d_in[0];
    const float* W3       = (const float*)d_in[1];
    const float* bias     = (const float*)d_in[2];
    const float* velocity = (const float*)d_in[3];
    const int*   I        = (const int*)d_in[4];
    const int*   J        = (const int*)d_in[5];
    const int E = in_sizes[1];
    const int N = in_sizes[3];
    float* out = (float*)d_out;

    const size_t mat_elems = (size_t)N * BATCH;
    const int NC   = (N + ROWS_PC - 1) / ROWS_PC;   // coarse buckets
    const int nseg = (N + SEG_ROWS - 1) / SEG_ROWS; // fine segments
    const int nb_n = (N + 63) / 64;
    const int nb_e = (E + PCHUNK - 1) / PCHUNK;
    const int nb_g = (nseg + 3) / 4;

    // ws: in_T | part | edges | coarse_hist | coarse_base | gcursor | seg_start
    const size_t need = mat_elems * sizeof(float)
                      + 2 * (size_t)E * sizeof(ull)
                      + (size_t)(NC + (NC + 1) + NC + NC * SEGS_PC) * sizeof(int);

    if (ws_size >= need && N <= 65535 && NC <= 256) {
        float* in_T        = (float*)d_ws;
        ull*   part        = (ull*)(in_T + mat_elems);
        ull*   edges       = part + E;
        int*   coarse_hist = (int*)(edges + E);
        int*   coarse_base = coarse_hist + NC;
        int*   gcursor     = coarse_base + NC + 1;
        int*   seg_start   = gcursor + NC;

        k_prep     <<<nb_n, 256, 0, stream>>>(inputs, in_T, coarse_hist, NC, N);
        k_hist     <<<nb_e, 256, 0, stream>>>(I, coarse_hist, E);
        k_scan     <<<1,    256, 0, stream>>>(coarse_hist, coarse_base, gcursor, NC);
        k_partition<<<nb_e, 256, 0, stream>>>(I, J, W3, velocity, gcursor, part, E);
        k_finesort <<<NC,   512, 0, stream>>>(part, coarse_base, edges, seg_start);
        k_gather   <<<nb_g, 256, 0, stream>>>(in_T, edges, seg_start, bias, out, nseg, N);
    } else {
        hipMemsetAsync(out, 0, (size_t)out_size * sizeof(float), stream);
        const int waves_needed   = (E + 63) / 64;
        const int scatter_blocks = (waves_needed + 3) / 4;
        k_edge_scatter_direct<<<scatter_blocks, 256, 0, stream>>>(inputs, W3, velocity, I, J, out, N, E);
        k_add_bias<<<(out_size + 255) / 256, 256, 0, stream>>>(bias, out, N, out_size);
    }
}